// Round 6
// baseline (557.976 us; speedup 1.0000x reference)
//
#include <hip/hip_runtime.h>
#include <stdint.h>

typedef __bf16 bf16;
typedef __bf16 bf16x4 __attribute__((ext_vector_type(4)));
typedef __bf16 bf16x8 __attribute__((ext_vector_type(8)));
typedef float f32x4 __attribute__((ext_vector_type(4)));
typedef short s16x4 __attribute__((ext_vector_type(4)));

using gp_t = __attribute__((address_space(1))) const void*;
using lp_t = __attribute__((address_space(3))) void*;

__device__ __forceinline__ void gld16(const void* g, void* l) {
  __builtin_amdgcn_global_load_lds((gp_t)g, (lp_t)l, 16, 0, 0);
}

// ---------------------------------------------------------------------------
// fp32 -> bf16 conversion, segment table (one kernel, grid-stride per segment)
// ---------------------------------------------------------------------------
struct CvtSegs {
  const float* src[10];
  bf16* dst[10];
  int cnt[10];     // element counts, divisible by 4
  int n;
};

__global__ void cvt_kernel(CvtSegs segs) {
  const int stride = gridDim.x * blockDim.x;
  const int t0 = blockIdx.x * blockDim.x + threadIdx.x;
  for (int s = 0; s < segs.n; s++) {
    const float4* src = (const float4*)segs.src[s];
    bf16x4* dst = (bf16x4*)segs.dst[s];
    int cnt4 = segs.cnt[s] >> 2;
    for (int idx = t0; idx < cnt4; idx += stride) {
      float4 v = src[idx];
      bf16x4 o; o[0] = (bf16)v.x; o[1] = (bf16)v.y; o[2] = (bf16)v.z; o[3] = (bf16)v.w;
      dst[idx] = o;
    }
  }
}

// ---------------------------------------------------------------------------
// 256x256-tile 8-wave GEMM, 4-phase K-loop (m201-family structure).
// C[M,N] = A[M,K] @ W[N,K]^T + bias[N], all bf16 in, fp32 accum.
// 512 threads = 8 waves (2M x 4N), per-wave output 128x64 (8x4 frags).
// LDS: A,B tiles 256x64 bf16, double-buffered = 128 KB -> 1 block/CU;
// latency hiding is IN-KERNEL: per K-tile 4 phases, each
//   {stage-half (ph 0,1) ; ds_read quadrant frags ; s_barrier ;
//    setprio(1) ; 16 MFMA ; setprio(0) ; [ph3: vmcnt(0)] ; s_barrier}
// Staging of tile t+1 is fully issued by phase 1 of tile t, so the
// boundary vmcnt(0) drains loads that have been in flight ~2.5 phases
// (NOT the m218 drain0 pathology, which drains same-phase loads).
// sched_barrier(0) after each s_barrier pins instruction motion (rule 18).
// 16B-chunk XOR swizzle on LDS, pre-swizzled global source (linear gld16
// dest + same-swizzle read: rule 21 satisfied).
// store_sel: 2 = fp32 row-major C (final output)
//            4 = fused QKV: col<2048 -> Q bf16 (b,s,h,d) at Cv
//                           col<2176 -> K (b,s,d) bf16 at Cv2
//                           else     -> V^T (b,d,s) bf16 at Cv3
// ---------------------------------------------------------------------------
__global__ __launch_bounds__(512, 2)
void gemm256(const bf16* __restrict__ A, const bf16* __restrict__ W,
             const bf16* __restrict__ bias, void* __restrict__ Cv,
             void* __restrict__ Cv2, void* __restrict__ Cv3,
             int N, int K, int store_sel)
{
  __shared__ __align__(16) bf16 As[2][256 * 64];
  __shared__ __align__(16) bf16 Bs[2][256 * 64];
  const int tid  = threadIdx.x;
  const int lane = tid & 63;
  const int w    = tid >> 6;           // 0..7
  const int wm   = w >> 2, wn = w & 3; // 2M x 4N wave grid
  const int quad = lane >> 4, l16 = lane & 15;
  const int m0 = blockIdx.x * 256, n0 = blockIdx.y * 256;

  f32x4 acc[8][4] = {};

  // stage two c-slots (one half-tile) of A and B each call.
  // c in [0,2048): row = c>>3 (0..255), chunk = (c&7)^(row&7)  [16B units]
  auto stageAB = [&](int buf, int k0, int itbase) {
#pragma unroll
    for (int it = itbase; it < itbase + 2; it++) {
      int c   = tid + it * 512;
      int row = c >> 3;
      int cc  = (c & 7) ^ (row & 7);
      gld16(A + (size_t)(m0 + row) * K + k0 + cc * 8, &As[buf][c * 8]);
      gld16(W + (size_t)(n0 + row) * K + k0 + cc * 8, &Bs[buf][c * 8]);
    }
  };

  // prologue: full tile 0; __syncthreads drains vmcnt+lgkmcnt and barriers
  stageAB(0, 0, 0);
  stageAB(0, 0, 2);
  __syncthreads();
  __builtin_amdgcn_sched_barrier(0);

  int cur = 0;
  for (int k0 = 0; k0 < K; k0 += 64) {
    const bool nxt = (k0 + 64 < K);
    bf16x8 bw[4][2];                   // B-frags [nj][dk], live all 4 phases
#pragma unroll
    for (int p = 0; p < 4; p++) {
      if (nxt && p < 2) stageAB(cur ^ 1, k0 + 64, p * 2);
      if (p == 0) {
#pragma unroll
        for (int nj = 0; nj < 4; nj++)
#pragma unroll
          for (int dk = 0; dk < 2; dk++) {
            int row = wn * 64 + nj * 16 + l16;
            bw[nj][dk] = *(const bf16x8*)&Bs[cur][(row * 8 + ((dk * 4 + quad) ^ (row & 7))) * 8];
          }
      }
      bf16x8 af[2][2];                 // A-frags for this quadrant
#pragma unroll
      for (int mi = 0; mi < 2; mi++)
#pragma unroll
        for (int dk = 0; dk < 2; dk++) {
          int row = wm * 128 + (p * 2 + mi) * 16 + l16;
          af[mi][dk] = *(const bf16x8*)&As[cur][(row * 8 + ((dk * 4 + quad) ^ (row & 7))) * 8];
        }
      __builtin_amdgcn_s_barrier();
      __builtin_amdgcn_sched_barrier(0);
      __builtin_amdgcn_s_setprio(1);
#pragma unroll
      for (int dk = 0; dk < 2; dk++)
#pragma unroll
        for (int mi = 0; mi < 2; mi++)
#pragma unroll
          for (int nj = 0; nj < 4; nj++)
            acc[p * 2 + mi][nj] = __builtin_amdgcn_mfma_f32_16x16x32_bf16(
                af[mi][dk], bw[nj][dk], acc[p * 2 + mi][nj], 0, 0, 0);
      __builtin_amdgcn_s_setprio(0);
      if (p == 3) asm volatile("s_waitcnt vmcnt(0)" ::: "memory");
      __builtin_amdgcn_s_barrier();
      __builtin_amdgcn_sched_barrier(0);
    }
    cur ^= 1;
  }

  // epilogue: C/D layout col=lane&15, row=quad*4+reg (m89/m91-verified)
#pragma unroll
  for (int nj = 0; nj < 4; nj++) {
    int col = n0 + wn * 64 + nj * 16 + l16;
    float bv = (float)bias[col];
#pragma unroll
    for (int mi = 0; mi < 8; mi++) {
#pragma unroll
      for (int r = 0; r < 4; r++) {
        int row = m0 + wm * 128 + mi * 16 + quad * 4 + r;
        float v = acc[mi][nj][r] + bv;
        if (store_sel == 2) {
          ((float*)Cv)[(size_t)row * N + col] = v;
        } else {   // fused QKV split (per-thread branch; col constant over mi,r)
          if (col < 2048) {
            ((bf16*)Cv)[(size_t)row * 2048 + col] = (bf16)v;             // Q (b,s,h,d)
          } else if (col < 2176) {
            ((bf16*)Cv2)[(size_t)row * 128 + (col - 2048)] = (bf16)v;    // K (b,s,d)
          } else {
            int b = row >> 11, s = row & 2047;   // S=2048 per batch
            ((bf16*)Cv3)[((size_t)(b * 128 + (col - 2176))) * 2048 + s] = (bf16)v; // V^T
          }
        }
      }
    }
  }
}

// ---------------------------------------------------------------------------
// Fallback 128x128 GEMM (fp32 W, fp32 bias, fp32 C) — only used for the
// O-projection when the workspace is too small for a bf16 weight copy.
// Single-buffered m97-style loop (round-3 form, known-pass).
// ---------------------------------------------------------------------------
__global__ __launch_bounds__(256, 2)
void gemm_bt_f32w(const bf16* __restrict__ A, const float* __restrict__ Wf,
                  const float* __restrict__ biasf, float* __restrict__ C,
                  int M, int N, int K)
{
  __shared__ __align__(16) bf16 As[128 * 64];
  __shared__ __align__(16) bf16 Bs[128 * 64];
  const int tid  = threadIdx.x;
  const int lane = tid & 63;
  const int w    = tid >> 6;
  const int wm   = w >> 1, wn = w & 1;
  const int quad = lane >> 4, l16 = lane & 15;
  const int m0 = blockIdx.x * 128, n0 = blockIdx.y * 128;

  f32x4 acc[4][4] = {};

  for (int k0 = 0; k0 < K; k0 += 64) {
#pragma unroll
    for (int it = 0; it < 4; it++) {
      int c = tid + it * 256;
      int row = c >> 3;
      int cc  = (c & 7) ^ (row & 7);
      gld16(A + (size_t)(m0 + row) * K + k0 + cc * 8, &As[c * 8]);
      size_t woff = (size_t)(n0 + row) * K + k0 + cc * 8;
      float4 x0 = *(const float4*)(Wf + woff);
      float4 x1 = *(const float4*)(Wf + woff + 4);
      bf16x8 v;
      v[0] = (bf16)x0.x; v[1] = (bf16)x0.y; v[2] = (bf16)x0.z; v[3] = (bf16)x0.w;
      v[4] = (bf16)x1.x; v[5] = (bf16)x1.y; v[6] = (bf16)x1.z; v[7] = (bf16)x1.w;
      *(bf16x8*)&Bs[c * 8] = v;
    }
    __syncthreads();
#pragma unroll
    for (int dk = 0; dk < 2; dk++) {
      bf16x8 af[4], bw[4];
#pragma unroll
      for (int i = 0; i < 4; i++) {
        int row = wm * 64 + i * 16 + l16;
        af[i] = *(const bf16x8*)&As[(row * 8 + ((dk * 4 + quad) ^ (row & 7))) * 8];
      }
#pragma unroll
      for (int j = 0; j < 4; j++) {
        int row = wn * 64 + j * 16 + l16;
        bw[j] = *(const bf16x8*)&Bs[(row * 8 + ((dk * 4 + quad) ^ (row & 7))) * 8];
      }
#pragma unroll
      for (int i = 0; i < 4; i++)
#pragma unroll
        for (int j = 0; j < 4; j++)
          acc[i][j] = __builtin_amdgcn_mfma_f32_16x16x32_bf16(af[i], bw[j], acc[i][j], 0, 0, 0);
    }
    __syncthreads();
  }

#pragma unroll
  for (int j = 0; j < 4; j++) {
    int col = n0 + wn * 64 + j * 16 + l16;
    float bv = biasf[col];
#pragma unroll
    for (int i = 0; i < 4; i++)
#pragma unroll
      for (int r = 0; r < 4; r++) {
        int row = m0 + wm * 64 + i * 16 + quad * 4 + r;
        C[(size_t)row * N + col] = acc[i][j][r] + bv;
      }
  }
}

// ---------------------------------------------------------------------------
// Causal MQA flash attention (unchanged, known-pass): swapped-operand
// softmax + register P + double-buffered K/V prefetch + setprio on MFMA.
// grid = (p=8, bh=64), block = 256 (4 waves); block p does qi = p and 15-p.
// ---------------------------------------------------------------------------
__global__ __launch_bounds__(256, 2)
void mqa_attn(const bf16* Qg, const bf16* __restrict__ Kg,
              const bf16* __restrict__ Vtg, bf16* AO)
{
  __shared__ __align__(16) bf16 Ks[2][64 * 128];
  __shared__ __align__(16) bf16 Vs[2][128 * 64];

  const int tid  = threadIdx.x;
  const int lane = tid & 63;
  const int w    = tid >> 6;
  const int quad = lane >> 4, l16 = lane & 15;
  const int rb   = w * 32;              // wave's q-row base within tile
  const int bh = blockIdx.y;
  const int b  = bh >> 4, h = bh & 15;
  const float C2  = 0.12751879526288147f;   // log2(e)/sqrt(128)
  const float NEG = -3.0e4f;                // finite mask value, exp2 -> 0

  for (int half = 0; half < 2; half++) {
    const int qi = half ? (15 - (int)blockIdx.x) : (int)blockIdx.x;
    const int q0 = qi * 128;

    // Q fragments (lane l16 = q-row, k = quad*8+e, dk = k-32-group)
    bf16x8 aq[2][4];
    {
      const bf16* qb = Qg + ((size_t)(b * 2048 + q0 + rb + l16)) * 2048 + h * 128 + quad * 8;
#pragma unroll
      for (int i = 0; i < 2; i++)
#pragma unroll
        for (int dk = 0; dk < 4; dk++)
          aq[i][dk] = *(const bf16x8*)(qb + (size_t)i * 16 * 2048 + dk * 32);
    }

    float m_reg[2] = {NEG, NEG};       // per q = i*16+l16 (replicated x4 quads)
    float l_reg[2] = {0.0f, 0.0f};
    f32x4 ot[2][8] = {};               // O^T: [i][jd], q=i*16+l16, d=jd*16+quad*4+r

    const int nt = 2 * qi + 2;

    // stage tile 0 into buffer 0
#pragma unroll
    for (int it = 0; it < 4; it++) {
      int c = tid + it * 256;
      int rk = c >> 4, ck = (c & 15) ^ (rk & 15);
      gld16(Kg + ((size_t)(b * 2048 + rk)) * 128 + ck * 8, &Ks[0][c * 8]);
      int rv = c >> 3, cv = (c & 7) ^ (rv & 7);
      gld16(Vtg + ((size_t)(b * 128 + rv)) * 2048 + cv * 8, &Vs[0][c * 8]);
    }
    __syncthreads();

    int cur = 0;
    for (int kt = 0; kt < nt; kt++) {
      const int kk0 = kt * 64;

      // prefetch next tile into other buffer; flies during compute below
      if (kt + 1 < nt) {
        const int nk0 = kk0 + 64;
#pragma unroll
        for (int it = 0; it < 4; it++) {
          int c = tid + it * 256;
          int rk = c >> 4, ck = (c & 15) ^ (rk & 15);
          gld16(Kg + ((size_t)(b * 2048 + nk0 + rk)) * 128 + ck * 8, &Ks[cur ^ 1][c * 8]);
          int rv = c >> 3, cv = (c & 7) ^ (rv & 7);
          gld16(Vtg + ((size_t)(b * 128 + rv)) * 2048 + nk0 + cv * 8, &Vs[cur ^ 1][c * 8]);
        }
      }

      if (kk0 <= q0 + rb + 31) {   // wave-uniform: skip fully-masked tiles
        // S^T = K Q^T : st[j][i] col=q=l16, row=key=j*16+quad*4+r
        f32x4 st[4][2] = {};
#pragma unroll
        for (int dk = 0; dk < 4; dk++) {
          bf16x8 bk[4];
#pragma unroll
          for (int j = 0; j < 4; j++) {
            int row = j * 16 + l16;   // key index
            bk[j] = *(const bf16x8*)&Ks[cur][(row * 16 + ((dk * 4 + quad) ^ (row & 15))) * 8];
          }
          __builtin_amdgcn_s_setprio(1);
#pragma unroll
          for (int j = 0; j < 4; j++)
#pragma unroll
            for (int i = 0; i < 2; i++)
              st[j][i] = __builtin_amdgcn_mfma_f32_16x16x32_bf16(bk[j], aq[i][dk], st[j][i], 0, 0, 0);
          __builtin_amdgcn_s_setprio(0);
        }

        if (kk0 + 63 > q0 + rb) {   // diagonal tile(s): causal mask (raw-s space)
#pragma unroll
          for (int j = 0; j < 4; j++)
#pragma unroll
            for (int i = 0; i < 2; i++)
#pragma unroll
              for (int r = 0; r < 4; r++) {
                int key = kk0 + j * 16 + quad * 4 + r;
                int qg  = q0 + rb + i * 16 + l16;
                if (key > qg) st[j][i][r] = NEG;
              }
        }

        // wave softmax (per i-block of 16 q-rows); P packed to bf16 in regs
        s16x4 ps[2][4];
#pragma unroll
        for (int i = 0; i < 2; i++) {
          float mx = st[0][i][0];
#pragma unroll
          for (int j = 0; j < 4; j++)
#pragma unroll
            for (int r = 0; r < 4; r++) mx = fmaxf(mx, st[j][i][r]);
          mx = fmaxf(mx, __shfl_xor(mx, 16, 64));
          mx = fmaxf(mx, __shfl_xor(mx, 32, 64));
          float mo = m_reg[i];
          if (__any(mx > mo)) {        // exact: alpha==1 when skipped
            float mn = fmaxf(mo, mx);
            float al = exp2f((mo - mn) * C2);
            l_reg[i] *= al;
#pragma unroll
            for (int jd = 0; jd < 8; jd++)
#pragma unroll
              for (int r = 0; r < 4; r++) ot[i][jd][r] *= al;
            m_reg[i] = mn;
          }
          float mc = m_reg[i] * C2;
          float rs = 0.0f;
#pragma unroll
          for (int j = 0; j < 4; j++) {
            float p0 = exp2f(st[j][i][0] * C2 - mc);
            float p1 = exp2f(st[j][i][1] * C2 - mc);
            float p2 = exp2f(st[j][i][2] * C2 - mc);
            float p3 = exp2f(st[j][i][3] * C2 - mc);
            rs += (p0 + p1) + (p2 + p3);
            union { bf16x4 h; s16x4 s; } pu;
            pu.h[0] = (bf16)p0; pu.h[1] = (bf16)p1;
            pu.h[2] = (bf16)p2; pu.h[3] = (bf16)p3;
            ps[i][j] = pu.s;
          }
          rs += __shfl_xor(rs, 16, 64);
          rs += __shfl_xor(rs, 32, 64);
          l_reg[i] += rs;
        }

        // O^T += V^T P^T : K=16 MFMAs; A=V-frag (m=d=l16, k=quad*4+e),
        // B=P^T-frag = this thread's own keys. No LDS for P.
#pragma unroll
        for (int jd = 0; jd < 8; jd++) {
          int vrow = jd * 16 + l16;   // d index
          s16x4 vf[4];
#pragma unroll
          for (int jk = 0; jk < 4; jk++) {
            int vch = (jk * 2 + (quad >> 1)) ^ (vrow & 7);
            vf[jk] = *(const s16x4*)&Vs[cur][(vrow * 8 + vch) * 8 + (quad & 1) * 4];
          }
          __builtin_amdgcn_s_setprio(1);
#pragma unroll
          for (int jk = 0; jk < 4; jk++)
#pragma unroll
            for (int i = 0; i < 2; i++)
              ot[i][jd] = __builtin_amdgcn_mfma_f32_16x16x16bf16_1k(vf[jk], ps[i][jk], ot[i][jd], 0, 0, 0);
          __builtin_amdgcn_s_setprio(0);
        }
      }
      __syncthreads();   // prefetch drained + all waves done with buffers[cur]
      cur ^= 1;
    }

    // epilogue: O^T / l, store bf16 (b,s,h,d); l indexed by l16 = q (no shuffle)
#pragma unroll
    for (int i = 0; i < 2; i++) {
      float l = l_reg[i];
      float inv = (l > 0.0f) ? 1.0f / l : 0.0f;
      size_t base = ((size_t)(b * 2048 + q0 + rb + i * 16 + l16)) * 2048 + h * 128 + quad * 4;
#pragma unroll
      for (int jd = 0; jd < 8; jd++) {
        bf16x4 ov;
#pragma unroll
        for (int r = 0; r < 4; r++) ov[r] = (bf16)(ot[i][jd][r] * inv);
        *(bf16x4*)(AO + base + jd * 16) = ov;
      }
    }
  }
}

// ---------------------------------------------------------------------------
// Memory plan.  Inputs/outputs are fp32.
//   d_ws  (>=32 MB known-safe): Qg/AO @0 (32 MB, in-place);
//         if ws_size >= 40.25 MB: wo_b @32M (8 MB) + ob_b @40M (4 KB)
//   d_out (64 MB fp32, dead until O-proj): Xb @0 (32 MB), Kg @32M (2 MB),
//         Vtg @34M (2 MB), wq_b @36M (8 MB), wkv_b @44M (1 MB, contiguous
//         after wq_b -> single 2304x2048 QKV weight), qb_b @45M (4 KB),
//         kvb_b right after (contiguous 2304-bias)
// Order: cvt -> fused QKV-proj (256^2) -> attention -> O-proj (256^2).
// ---------------------------------------------------------------------------
extern "C" void kernel_launch(void* const* d_in, const int* in_sizes, int n_in,
                              void* d_out, int out_size, void* d_ws, size_t ws_size,
                              hipStream_t stream)
{
  const float* X   = (const float*)d_in[0];
  const float* q_w = (const float*)d_in[1];
  const float* q_b = (const float*)d_in[2];
  const float* k_w = (const float*)d_in[3];
  const float* k_b = (const float*)d_in[4];
  const float* v_w = (const float*)d_in[5];
  const float* v_b = (const float*)d_in[6];
  const float* o_w = (const float*)d_in[7];
  const float* o_b = (const float*)d_in[8];

  char* outc = (char*)d_out;
  bf16* Xb    = (bf16*)(outc);                       // 8192 x 2048
  bf16* Kg    = (bf16*)(outc + 33554432);            // 8192 x 128 (b,s,d)
  bf16* Vtg   = (bf16*)(outc + 35651584);            // 4 x 128 x 2048 V^T
  bf16* wq_b  = (bf16*)(outc + 37748736);            // 2048 x 2048
  bf16* wkv_b = (bf16*)(outc + 46137344);            // 256 x 2048 (contig after wq_b)
  bf16* qb_b  = (bf16*)(outc + 47185920);            // 2048
  bf16* kvb_b = (bf16*)(outc + 47190016);            // 256 (contig after qb_b)

  bf16* Qg = (bf16*)d_ws;                            // 8192 x 2048; AO in-place
  bf16* AO = Qg;

  const bool big_ws = ws_size >= (size_t)(33554432 + 8388608 + 8192);
  bf16* wo_b = big_ws ? (bf16*)((char*)d_ws + 33554432) : nullptr;
  bf16* ob_b = big_ws ? (bf16*)((char*)d_ws + 41943040) : nullptr;

  CvtSegs segs;
  int n = 0;
  segs.src[n] = X;   segs.dst[n] = Xb;            segs.cnt[n] = 16777216; n++;
  segs.src[n] = q_w; segs.dst[n] = wq_b;          segs.cnt[n] = 4194304;  n++;
  segs.src[n] = k_w; segs.dst[n] = wkv_b;         segs.cnt[n] = 262144;   n++;
  segs.src[n] = v_w; segs.dst[n] = wkv_b + 262144; segs.cnt[n] = 262144;  n++;
  segs.src[n] = q_b; segs.dst[n] = qb_b;          segs.cnt[n] = 2048;     n++;
  segs.src[n] = k_b; segs.dst[n] = kvb_b;         segs.cnt[n] = 128;      n++;
  segs.src[n] = v_b; segs.dst[n] = kvb_b + 128;   segs.cnt[n] = 128;      n++;
  if (big_ws) {
    segs.src[n] = o_w; segs.dst[n] = wo_b;        segs.cnt[n] = 4194304;  n++;
    segs.src[n] = o_b; segs.dst[n] = ob_b;        segs.cnt[n] = 2048;     n++;
  }
  segs.n = n;

  cvt_kernel<<<dim3(1024), dim3(256), 0, stream>>>(segs);
  // fused Q+KV projection: W = [wq_b; wkv_b] 2304x2048, bias = [qb_b; kvb_b]
  gemm256<<<dim3(32, 9), dim3(512), 0, stream>>>(Xb, wq_b, qb_b, Qg, Kg, Vtg,
                                                 2304, 2048, 4);
  mqa_attn<<<dim3(8, 64), dim3(256), 0, stream>>>(Qg, Kg, Vtg, AO);
  if (big_ws)
    gemm256<<<dim3(32, 8), dim3(512), 0, stream>>>(AO, wo_b, ob_b, d_out,
                                                   nullptr, nullptr, 2048, 2048, 2);
  else
    gemm_bt_f32w<<<dim3(64, 16), dim3(256), 0, stream>>>(AO, o_w, o_b, (float*)d_out,
                                                         8192, 2048, 2048);
}

// Round 7
// 546.881 us; speedup vs baseline: 1.0203x; 1.0203x over previous
//
#include <hip/hip_runtime.h>
#include <stdint.h>

typedef __bf16 bf16;
typedef __bf16 bf16x4 __attribute__((ext_vector_type(4)));
typedef __bf16 bf16x8 __attribute__((ext_vector_type(8)));
typedef float f32x4 __attribute__((ext_vector_type(4)));
typedef short s16x4 __attribute__((ext_vector_type(4)));

using gp_t = __attribute__((address_space(1))) const void*;
using lp_t = __attribute__((address_space(3))) void*;

__device__ __forceinline__ void gld16(const void* g, void* l) {
  __builtin_amdgcn_global_load_lds((gp_t)g, (lp_t)l, 16, 0, 0);
}

// ---------------------------------------------------------------------------
// fp32 -> bf16 conversion, segment table (one kernel, grid-stride per segment)
// ---------------------------------------------------------------------------
struct CvtSegs {
  const float* src[10];
  bf16* dst[10];
  int cnt[10];     // element counts, divisible by 4
  int n;
};

__global__ void cvt_kernel(CvtSegs segs) {
  const int stride = gridDim.x * blockDim.x;
  const int t0 = blockIdx.x * blockDim.x + threadIdx.x;
  for (int s = 0; s < segs.n; s++) {
    const float4* src = (const float4*)segs.src[s];
    bf16x4* dst = (bf16x4*)segs.dst[s];
    int cnt4 = segs.cnt[s] >> 2;
    for (int idx = t0; idx < cnt4; idx += stride) {
      float4 v = src[idx];
      bf16x4 o; o[0] = (bf16)v.x; o[1] = (bf16)v.y; o[2] = (bf16)v.z; o[3] = (bf16)v.w;
      dst[idx] = o;
    }
  }
}

// ---------------------------------------------------------------------------
// 256x256-tile 8-wave GEMM, v2: K-step 32, 4-deep LDS ring, stage 3 tiles
// ahead, ONE counted vmcnt + ONE barrier per K-step.
//   Per-wave pipeline (m135 vmcnt semantics): entering tile t, loads for
//   t+1,t+2,t+3 are in flight (12). End-of-tile s_waitcnt vmcnt(8) waits
//   EXACTLY tile t+1's 4 loads — issued 3 tiles (~900+ cyc) earlier, >= HBM
//   latency — and never the younger 8.  This is the m201 "counted, never 0"
//   mechanism; round-6's failure was issue-to-wait of only ~300-460 cyc with
//   a full drain.  Tail peels vmcnt(4)/vmcnt(0) for the last two boundaries.
// Cross-wave safety: all waves run the identical schedule, so after each
// wave's counted wait + the barrier, every wave's loads into the tile about
// to be read have landed.  Stores during tile t target ring slot (t+3)&3,
// which was last read at tile t-1 (ds_reads completed pre-barrier).
// LDS swizzle (2-bit + parity): slot(row, lp) holds logical k-chunk
// lp ^ ((row>>1)&3) -> banks distinct across 8 consecutive rows, rows 8
// apart 2-way-alias (free, m136).  Same XOR on stage source + ds_read.
// XCD swizzle (chunked, bijective for gridDim.x=32, nwg%8==0): XCD k owns
// m-tiles [4k,4k+4) x all n-tiles -> 4 A-panels (4 MB) pinned in that
// XCD's L2; A refetch becomes ~200cyc L2 hits inside the 3-tile cover.
// store_sel: 2 = fp32 row-major C (final output)
//            4 = fused QKV: col<2048 -> Q bf16 (b,s,h,d) at Cv
//                           col<2176 -> K (b,s,d) bf16 at Cv2
//                           else     -> V^T (b,d,s) bf16 at Cv3
// ---------------------------------------------------------------------------
__global__ __launch_bounds__(512, 1)
void gemm256(const bf16* __restrict__ A, const bf16* __restrict__ W,
             const bf16* __restrict__ bias, void* __restrict__ Cv,
             void* __restrict__ Cv2, void* __restrict__ Cv3,
             int N, int K, int store_sel)
{
  __shared__ __align__(16) bf16 As[4][256 * 32];
  __shared__ __align__(16) bf16 Bs[4][256 * 32];
  const int tid  = threadIdx.x;
  const int lane = tid & 63;
  const int w    = tid >> 6;           // 0..7
  const int wm   = w >> 2, wn = w & 3; // 2M x 4N wave grid
  const int quad = lane >> 4, l16 = lane & 15;

  // XCD-aware chunked block swizzle (HW round-robins bid%8 across XCDs)
  const int bid = (int)blockIdx.x + 32 * (int)blockIdx.y;
  const int xcd = bid & 7, t8 = bid >> 3;
  const int m0 = (xcd * 4 + (t8 & 3)) * 256;
  const int n0 = (t8 >> 2) * 256;

  f32x4 acc[8][4] = {};

  // stage one 32-K tile of A and B (4 gld16/thread).
  // slot c: row=c>>2, lp=c&3; holds logical chunk cc = lp ^ ((row>>1)&3).
  auto stage = [&](int buf, int k0) {
#pragma unroll
    for (int it = 0; it < 2; it++) {
      int c   = tid + it * 512;        // 1024 slots = 256 rows x 4 chunks
      int row = c >> 2;
      int cc  = (c & 3) ^ ((row >> 1) & 3);
      gld16(A + (size_t)(m0 + row) * K + k0 + cc * 8, &As[buf][c * 8]);
      gld16(W + (size_t)(n0 + row) * K + k0 + cc * 8, &Bs[buf][c * 8]);
    }
  };

  const int nT = K >> 5;               // 64 K-steps

  // prologue: stage tiles 0,1,2; wait tile 0 only (8 loads stay in flight)
  stage(0, 0); stage(1, 32); stage(2, 64);
  asm volatile("s_waitcnt vmcnt(8)" ::: "memory");
  __builtin_amdgcn_s_barrier();
  __builtin_amdgcn_sched_barrier(0);

  for (int t = 0; t < nT; t++) {
    const int buf = t & 3;
    if (t + 3 < nT) stage((t + 3) & 3, (t + 3) << 5);

    // B-frags once per tile; A-frags per mi-half
    bf16x8 bw[4];
#pragma unroll
    for (int j = 0; j < 4; j++) {
      int row = wn * 64 + j * 16 + l16;
      bw[j] = *(const bf16x8*)&Bs[buf][(row * 4 + (quad ^ ((row >> 1) & 3))) * 8];
    }
#pragma unroll
    for (int h = 0; h < 2; h++) {
      bf16x8 af[4];
#pragma unroll
      for (int i = 0; i < 4; i++) {
        int row = wm * 128 + (h * 4 + i) * 16 + l16;
        af[i] = *(const bf16x8*)&As[buf][(row * 4 + (quad ^ ((row >> 1) & 3))) * 8];
      }
      __builtin_amdgcn_s_setprio(1);
#pragma unroll
      for (int i = 0; i < 4; i++)
#pragma unroll
        for (int j = 0; j < 4; j++)
          acc[h * 4 + i][j] = __builtin_amdgcn_mfma_f32_16x16x32_bf16(
              af[i], bw[j], acc[h * 4 + i][j], 0, 0, 0);
      __builtin_amdgcn_s_setprio(0);
    }

    // counted wait: drain ONLY tile t+1's group (issued 3 tiles ago)
    if (t < nT - 3)       asm volatile("s_waitcnt vmcnt(8)" ::: "memory");
    else if (t == nT - 3) asm volatile("s_waitcnt vmcnt(4)" ::: "memory");
    else if (t == nT - 2) asm volatile("s_waitcnt vmcnt(0)" ::: "memory");
    if (t < nT - 1) {
      __builtin_amdgcn_s_barrier();
      __builtin_amdgcn_sched_barrier(0);
    }
  }

  // epilogue: C/D layout col=lane&15, row=quad*4+reg (m89/m91-verified)
#pragma unroll
  for (int nj = 0; nj < 4; nj++) {
    int col = n0 + wn * 64 + nj * 16 + l16;
    float bv = (float)bias[col];
#pragma unroll
    for (int mi = 0; mi < 8; mi++) {
#pragma unroll
      for (int r = 0; r < 4; r++) {
        int row = m0 + wm * 128 + mi * 16 + quad * 4 + r;
        float v = acc[mi][nj][r] + bv;
        if (store_sel == 2) {
          ((float*)Cv)[(size_t)row * N + col] = v;
        } else {   // fused QKV split (col constant over mi,r)
          if (col < 2048) {
            ((bf16*)Cv)[(size_t)row * 2048 + col] = (bf16)v;             // Q (b,s,h,d)
          } else if (col < 2176) {
            ((bf16*)Cv2)[(size_t)row * 128 + (col - 2048)] = (bf16)v;    // K (b,s,d)
          } else {
            int b = row >> 11, s = row & 2047;   // S=2048 per batch
            ((bf16*)Cv3)[((size_t)(b * 128 + (col - 2176))) * 2048 + s] = (bf16)v; // V^T
          }
        }
      }
    }
  }
}

// ---------------------------------------------------------------------------
// Fallback 128x128 GEMM (fp32 W, fp32 bias, fp32 C) — only used for the
// O-projection when the workspace is too small for a bf16 weight copy.
// Single-buffered m97-style loop (round-3 form, known-pass).
// ---------------------------------------------------------------------------
__global__ __launch_bounds__(256, 2)
void gemm_bt_f32w(const bf16* __restrict__ A, const float* __restrict__ Wf,
                  const float* __restrict__ biasf, float* __restrict__ C,
                  int M, int N, int K)
{
  __shared__ __align__(16) bf16 As[128 * 64];
  __shared__ __align__(16) bf16 Bs[128 * 64];
  const int tid  = threadIdx.x;
  const int lane = tid & 63;
  const int w    = tid >> 6;
  const int wm   = w >> 1, wn = w & 1;
  const int quad = lane >> 4, l16 = lane & 15;
  const int m0 = blockIdx.x * 128, n0 = blockIdx.y * 128;

  f32x4 acc[4][4] = {};

  for (int k0 = 0; k0 < K; k0 += 64) {
#pragma unroll
    for (int it = 0; it < 4; it++) {
      int c = tid + it * 256;
      int row = c >> 3;
      int cc  = (c & 7) ^ (row & 7);
      gld16(A + (size_t)(m0 + row) * K + k0 + cc * 8, &As[c * 8]);
      size_t woff = (size_t)(n0 + row) * K + k0 + cc * 8;
      float4 x0 = *(const float4*)(Wf + woff);
      float4 x1 = *(const float4*)(Wf + woff + 4);
      bf16x8 v;
      v[0] = (bf16)x0.x; v[1] = (bf16)x0.y; v[2] = (bf16)x0.z; v[3] = (bf16)x0.w;
      v[4] = (bf16)x1.x; v[5] = (bf16)x1.y; v[6] = (bf16)x1.z; v[7] = (bf16)x1.w;
      *(bf16x8*)&Bs[c * 8] = v;
    }
    __syncthreads();
#pragma unroll
    for (int dk = 0; dk < 2; dk++) {
      bf16x8 af[4], bw[4];
#pragma unroll
      for (int i = 0; i < 4; i++) {
        int row = wm * 64 + i * 16 + l16;
        af[i] = *(const bf16x8*)&As[(row * 8 + ((dk * 4 + quad) ^ (row & 7))) * 8];
      }
#pragma unroll
      for (int j = 0; j < 4; j++) {
        int row = wn * 64 + j * 16 + l16;
        bw[j] = *(const bf16x8*)&Bs[(row * 8 + ((dk * 4 + quad) ^ (row & 7))) * 8];
      }
#pragma unroll
      for (int i = 0; i < 4; i++)
#pragma unroll
        for (int j = 0; j < 4; j++)
          acc[i][j] = __builtin_amdgcn_mfma_f32_16x16x32_bf16(af[i], bw[j], acc[i][j], 0, 0, 0);
    }
    __syncthreads();
  }

#pragma unroll
  for (int j = 0; j < 4; j++) {
    int col = n0 + wn * 64 + j * 16 + l16;
    float bv = biasf[col];
#pragma unroll
    for (int i = 0; i < 4; i++)
#pragma unroll
      for (int r = 0; r < 4; r++) {
        int row = m0 + wm * 64 + i * 16 + quad * 4 + r;
        C[(size_t)row * N + col] = acc[i][j][r] + bv;
      }
  }
}

// ---------------------------------------------------------------------------
// Causal MQA flash attention (unchanged, known-pass): swapped-operand
// softmax + register P + double-buffered K/V prefetch + setprio on MFMA.
// grid = (p=8, bh=64), block = 256 (4 waves); block p does qi = p and 15-p.
// ---------------------------------------------------------------------------
__global__ __launch_bounds__(256, 2)
void mqa_attn(const bf16* Qg, const bf16* __restrict__ Kg,
              const bf16* __restrict__ Vtg, bf16* AO)
{
  __shared__ __align__(16) bf16 Ks[2][64 * 128];
  __shared__ __align__(16) bf16 Vs[2][128 * 64];

  const int tid  = threadIdx.x;
  const int lane = tid & 63;
  const int w    = tid >> 6;
  const int quad = lane >> 4, l16 = lane & 15;
  const int rb   = w * 32;              // wave's q-row base within tile
  const int bh = blockIdx.y;
  const int b  = bh >> 4, h = bh & 15;
  const float C2  = 0.12751879526288147f;   // log2(e)/sqrt(128)
  const float NEG = -3.0e4f;                // finite mask value, exp2 -> 0

  for (int half = 0; half < 2; half++) {
    const int qi = half ? (15 - (int)blockIdx.x) : (int)blockIdx.x;
    const int q0 = qi * 128;

    // Q fragments (lane l16 = q-row, k = quad*8+e, dk = k-32-group)
    bf16x8 aq[2][4];
    {
      const bf16* qb = Qg + ((size_t)(b * 2048 + q0 + rb + l16)) * 2048 + h * 128 + quad * 8;
#pragma unroll
      for (int i = 0; i < 2; i++)
#pragma unroll
        for (int dk = 0; dk < 4; dk++)
          aq[i][dk] = *(const bf16x8*)(qb + (size_t)i * 16 * 2048 + dk * 32);
    }

    float m_reg[2] = {NEG, NEG};       // per q = i*16+l16 (replicated x4 quads)
    float l_reg[2] = {0.0f, 0.0f};
    f32x4 ot[2][8] = {};               // O^T: [i][jd], q=i*16+l16, d=jd*16+quad*4+r

    const int nt = 2 * qi + 2;

    // stage tile 0 into buffer 0
#pragma unroll
    for (int it = 0; it < 4; it++) {
      int c = tid + it * 256;
      int rk = c >> 4, ck = (c & 15) ^ (rk & 15);
      gld16(Kg + ((size_t)(b * 2048 + rk)) * 128 + ck * 8, &Ks[0][c * 8]);
      int rv = c >> 3, cv = (c & 7) ^ (rv & 7);
      gld16(Vtg + ((size_t)(b * 128 + rv)) * 2048 + cv * 8, &Vs[0][c * 8]);
    }
    __syncthreads();

    int cur = 0;
    for (int kt = 0; kt < nt; kt++) {
      const int kk0 = kt * 64;

      // prefetch next tile into other buffer; flies during compute below
      if (kt + 1 < nt) {
        const int nk0 = kk0 + 64;
#pragma unroll
        for (int it = 0; it < 4; it++) {
          int c = tid + it * 256;
          int rk = c >> 4, ck = (c & 15) ^ (rk & 15);
          gld16(Kg + ((size_t)(b * 2048 + nk0 + rk)) * 128 + ck * 8, &Ks[cur ^ 1][c * 8]);
          int rv = c >> 3, cv = (c & 7) ^ (rv & 7);
          gld16(Vtg + ((size_t)(b * 128 + rv)) * 2048 + nk0 + cv * 8, &Vs[cur ^ 1][c * 8]);
        }
      }

      if (kk0 <= q0 + rb + 31) {   // wave-uniform: skip fully-masked tiles
        // S^T = K Q^T : st[j][i] col=q=l16, row=key=j*16+quad*4+r
        f32x4 st[4][2] = {};
#pragma unroll
        for (int dk = 0; dk < 4; dk++) {
          bf16x8 bk[4];
#pragma unroll
          for (int j = 0; j < 4; j++) {
            int row = j * 16 + l16;   // key index
            bk[j] = *(const bf16x8*)&Ks[cur][(row * 16 + ((dk * 4 + quad) ^ (row & 15))) * 8];
          }
          __builtin_amdgcn_s_setprio(1);
#pragma unroll
          for (int j = 0; j < 4; j++)
#pragma unroll
            for (int i = 0; i < 2; i++)
              st[j][i] = __builtin_amdgcn_mfma_f32_16x16x32_bf16(bk[j], aq[i][dk], st[j][i], 0, 0, 0);
          __builtin_amdgcn_s_setprio(0);
        }

        if (kk0 + 63 > q0 + rb) {   // diagonal tile(s): causal mask (raw-s space)
#pragma unroll
          for (int j = 0; j < 4; j++)
#pragma unroll
            for (int i = 0; i < 2; i++)
#pragma unroll
              for (int r = 0; r < 4; r++) {
                int key = kk0 + j * 16 + quad * 4 + r;
                int qg  = q0 + rb + i * 16 + l16;
                if (key > qg) st[j][i][r] = NEG;
              }
        }

        // wave softmax (per i-block of 16 q-rows); P packed to bf16 in regs
        s16x4 ps[2][4];
#pragma unroll
        for (int i = 0; i < 2; i++) {
          float mx = st[0][i][0];
#pragma unroll
          for (int j = 0; j < 4; j++)
#pragma unroll
            for (int r = 0; r < 4; r++) mx = fmaxf(mx, st[j][i][r]);
          mx = fmaxf(mx, __shfl_xor(mx, 16, 64));
          mx = fmaxf(mx, __shfl_xor(mx, 32, 64));
          float mo = m_reg[i];
          if (__any(mx > mo)) {        // exact: alpha==1 when skipped
            float mn = fmaxf(mo, mx);
            float al = exp2f((mo - mn) * C2);
            l_reg[i] *= al;
#pragma unroll
            for (int jd = 0; jd < 8; jd++)
#pragma unroll
              for (int r = 0; r < 4; r++) ot[i][jd][r] *= al;
            m_reg[i] = mn;
          }
          float mc = m_reg[i] * C2;
          float rs = 0.0f;
#pragma unroll
          for (int j = 0; j < 4; j++) {
            float p0 = exp2f(st[j][i][0] * C2 - mc);
            float p1 = exp2f(st[j][i][1] * C2 - mc);
            float p2 = exp2f(st[j][i][2] * C2 - mc);
            float p3 = exp2f(st[j][i][3] * C2 - mc);
            rs += (p0 + p1) + (p2 + p3);
            union { bf16x4 h; s16x4 s; } pu;
            pu.h[0] = (bf16)p0; pu.h[1] = (bf16)p1;
            pu.h[2] = (bf16)p2; pu.h[3] = (bf16)p3;
            ps[i][j] = pu.s;
          }
          rs += __shfl_xor(rs, 16, 64);
          rs += __shfl_xor(rs, 32, 64);
          l_reg[i] += rs;
        }

        // O^T += V^T P^T : K=16 MFMAs; A=V-frag (m=d=l16, k=quad*4+e),
        // B=P^T-frag = this thread's own keys. No LDS for P.
#pragma unroll
        for (int jd = 0; jd < 8; jd++) {
          int vrow = jd * 16 + l16;   // d index
          s16x4 vf[4];
#pragma unroll
          for (int jk = 0; jk < 4; jk++) {
            int vch = (jk * 2 + (quad >> 1)) ^ (vrow & 7);
            vf[jk] = *(const s16x4*)&Vs[cur][(vrow * 8 + vch) * 8 + (quad & 1) * 4];
          }
          __builtin_amdgcn_s_setprio(1);
#pragma unroll
          for (int jk = 0; jk < 4; jk++)
#pragma unroll
            for (int i = 0; i < 2; i++)
              ot[i][jd] = __builtin_amdgcn_mfma_f32_16x16x16bf16_1k(vf[jk], ps[i][jk], ot[i][jd], 0, 0, 0);
          __builtin_amdgcn_s_setprio(0);
        }
      }
      __syncthreads();   // prefetch drained + all waves done with buffers[cur]
      cur ^= 1;
    }

    // epilogue: O^T / l, store bf16 (b,s,h,d); l indexed by l16 = q (no shuffle)
#pragma unroll
    for (int i = 0; i < 2; i++) {
      float l = l_reg[i];
      float inv = (l > 0.0f) ? 1.0f / l : 0.0f;
      size_t base = ((size_t)(b * 2048 + q0 + rb + i * 16 + l16)) * 2048 + h * 128 + quad * 4;
#pragma unroll
      for (int jd = 0; jd < 8; jd++) {
        bf16x4 ov;
#pragma unroll
        for (int r = 0; r < 4; r++) ov[r] = (bf16)(ot[i][jd][r] * inv);
        *(bf16x4*)(AO + base + jd * 16) = ov;
      }
    }
  }
}

// ---------------------------------------------------------------------------
// Memory plan.  Inputs/outputs are fp32.
//   d_ws  (>=32 MB known-safe): Qg/AO @0 (32 MB, in-place);
//         if ws_size >= 40.25 MB: wo_b @32M (8 MB) + ob_b @40M (4 KB)
//   d_out (64 MB fp32, dead until O-proj): Xb @0 (32 MB), Kg @32M (2 MB),
//         Vtg @34M (2 MB), wq_b @36M (8 MB), wkv_b @44M (1 MB, contiguous
//         after wq_b -> single 2304x2048 QKV weight), qb_b @45M (4 KB),
//         kvb_b right after (contiguous 2304-bias)
// Order: cvt -> fused QKV-proj (256^2) -> attention -> O-proj (256^2).
// ---------------------------------------------------------------------------
extern "C" void kernel_launch(void* const* d_in, const int* in_sizes, int n_in,
                              void* d_out, int out_size, void* d_ws, size_t ws_size,
                              hipStream_t stream)
{
  const float* X   = (const float*)d_in[0];
  const float* q_w = (const float*)d_in[1];
  const float* q_b = (const float*)d_in[2];
  const float* k_w = (const float*)d_in[3];
  const float* k_b = (const float*)d_in[4];
  const float* v_w = (const float*)d_in[5];
  const float* v_b = (const float*)d_in[6];
  const float* o_w = (const float*)d_in[7];
  const float* o_b = (const float*)d_in[8];

  char* outc = (char*)d_out;
  bf16* Xb    = (bf16*)(outc);                       // 8192 x 2048
  bf16* Kg    = (bf16*)(outc + 33554432);            // 8192 x 128 (b,s,d)
  bf16* Vtg   = (bf16*)(outc + 35651584);            // 4 x 128 x 2048 V^T
  bf16* wq_b  = (bf16*)(outc + 37748736);            // 2048 x 2048
  bf16* wkv_b = (bf16*)(outc + 46137344);            // 256 x 2048 (contig after wq_b)
  bf16* qb_b  = (bf16*)(outc + 47185920);            // 2048
  bf16* kvb_b = (bf16*)(outc + 47190016);            // 256 (contig after qb_b)

  bf16* Qg = (bf16*)d_ws;                            // 8192 x 2048; AO in-place
  bf16* AO = Qg;

  const bool big_ws = ws_size >= (size_t)(33554432 + 8388608 + 8192);
  bf16* wo_b = big_ws ? (bf16*)((char*)d_ws + 33554432) : nullptr;
  bf16* ob_b = big_ws ? (bf16*)((char*)d_ws + 41943040) : nullptr;

  CvtSegs segs;
  int n = 0;
  segs.src[n] = X;   segs.dst[n] = Xb;            segs.cnt[n] = 16777216; n++;
  segs.src[n] = q_w; segs.dst[n] = wq_b;          segs.cnt[n] = 4194304;  n++;
  segs.src[n] = k_w; segs.dst[n] = wkv_b;         segs.cnt[n] = 262144;   n++;
  segs.src[n] = v_w; segs.dst[n] = wkv_b + 262144; segs.cnt[n] = 262144;  n++;
  segs.src[n] = q_b; segs.dst[n] = qb_b;          segs.cnt[n] = 2048;     n++;
  segs.src[n] = k_b; segs.dst[n] = kvb_b;         segs.cnt[n] = 128;      n++;
  segs.src[n] = v_b; segs.dst[n] = kvb_b + 128;   segs.cnt[n] = 128;      n++;
  if (big_ws) {
    segs.src[n] = o_w; segs.dst[n] = wo_b;        segs.cnt[n] = 4194304;  n++;
    segs.src[n] = o_b; segs.dst[n] = ob_b;        segs.cnt[n] = 2048;     n++;
  }
  segs.n = n;

  cvt_kernel<<<dim3(1024), dim3(256), 0, stream>>>(segs);
  // fused Q+KV projection: W = [wq_b; wkv_b] 2304x2048, bias = [qb_b; kvb_b]
  gemm256<<<dim3(32, 9), dim3(512), 0, stream>>>(Xb, wq_b, qb_b, Qg, Kg, Vtg,
                                                 2304, 2048, 4);
  mqa_attn<<<dim3(8, 64), dim3(256), 0, stream>>>(Qg, Kg, Vtg, AO);
  if (big_ws)
    gemm256<<<dim3(32, 8), dim3(512), 0, stream>>>(AO, wo_b, ob_b, d_out,
                                                   nullptr, nullptr, 2048, 2048, 2);
  else
    gemm_bt_f32w<<<dim3(64, 16), dim3(256), 0, stream>>>(AO, o_w, o_b, (float*)d_out,
                                                         8192, 2048, 2048);
}